// Round 4
// baseline (358.105 us; speedup 1.0000x reference)
//
#include <hip/hip_runtime.h>

typedef float v2f __attribute__((ext_vector_type(2)));

#define RAD 5
#define BX 32              // output tile width (pixels)
#define BY 16              // output tile height
#define PX 2               // pixels per thread in x
#define NTX 16             // threads in x (NTX*PX == BX)
#define TW (BX + 2*RAD)    // 42 halo tile width
#define TH (BY + 2*RAD)    // 26 halo tile height
#define TWP (TW + 1)       // 43 padded LDS row stride

#define LOG2E 1.44269504f
#define CLAMP2 14426.950f  // 1e4 * log2(e)

// kLG[|d|] = log2(exp(-d*d/8)) = -d*d/(8*ln2)
__device__ __constant__ const float kLG[6] = {
    0.0f, -0.18033688f, -0.72134752f, -1.62303192f, -2.88539008f, -4.50842200f};
// kINVD[|dy|][|dx|] = 1/sqrt(dy^2+dx^2); center sentinel 1e30 -> min() clamps
__device__ __constant__ const float kINVD[6][6] = {
    {1e30f,       1.0f,        0.5f,        0.33333333f, 0.25f,       0.2f},
    {1.0f,        0.70710678f, 0.44721360f, 0.31622777f, 0.24253563f, 0.19611614f},
    {0.5f,        0.44721360f, 0.35355339f, 0.27735010f, 0.22360680f, 0.18569534f},
    {0.33333333f, 0.31622777f, 0.27735010f, 0.23570226f, 0.2f,        0.17149859f},
    {0.25f,       0.24253563f, 0.22360680f, 0.2f,        0.17677670f, 0.15617376f},
    {0.2f,        0.19611614f, 0.18569534f, 0.17149859f, 0.15617376f, 0.14142136f}};

__device__ __forceinline__ v2f splat(float s) { v2f r; r.x = s; r.y = s; return r; }

__global__ __launch_bounds__(256, 4) void bilateral_kernel(
    const float* __restrict__ col, const float* __restrict__ nrm,
    const float* __restrict__ zdz, float* __restrict__ out,
    int H, int W) {
  __shared__ float4 s_a[TH][TWP];  // col.rgb, z
  __shared__ float4 s_b[TH][TWP];  // nrm.xyz, dz

  const int bx = blockIdx.x, by = blockIdx.y, bz = blockIdx.z;
  const int gx0 = bx * BX - RAD;
  const int gy0 = by * BY - RAD;
  const int tid = threadIdx.x;
  const int plane = bz * H * W;

  // ---- stage halo tile into LDS (OOB -> zeros => weight 0, matches mask) ----
  for (int i = tid; i < TH * TW; i += 256) {
    const int r = i / TW;
    const int c = i - r * TW;
    const int gy = gy0 + r, gx = gx0 + c;
    float4 a = make_float4(0.f, 0.f, 0.f, 0.f);
    float4 b = make_float4(0.f, 0.f, 0.f, 0.f);
    if ((unsigned)gy < (unsigned)H && (unsigned)gx < (unsigned)W) {
      const int pix = plane + gy * W + gx;
      const float* cp = col + pix * 3;
      a.x = cp[0]; a.y = cp[1]; a.z = cp[2];
      const float* np_ = nrm + pix * 3;
      b.x = np_[0]; b.y = np_[1]; b.z = np_[2];
      const float* zp = zdz + pix * 2;
      a.w = zp[0]; b.w = zp[1];
    }
    s_a[r][c] = a;
    s_b[r][c] = b;
  }
  __syncthreads();

  const int tx = tid & (NTX - 1);
  const int ty = tid >> 4;
  const int ly = ty + RAD;
  const int lxbase = tx * PX;  // tap x = lxbase + u ; center p at lxbase+RAD+p

  // packed per-thread center state: half .x = pixel p=0, half .y = p=1
  v2f cnx, cny, cnz, cz2, rc2;
  v2f accx = splat(0.f), accy = splat(0.f), accz = splat(0.f), accw = splat(0.f);
  {
    const float4 a0 = s_a[ly][lxbase + RAD + 0];
    const float4 b0 = s_b[ly][lxbase + RAD + 0];
    const float4 a1 = s_a[ly][lxbase + RAD + 1];
    const float4 b1 = s_b[ly][lxbase + RAD + 1];
    cnx.x = b0.x; cnx.y = b1.x;
    cny.x = b0.y; cny.y = b1.y;
    cnz.x = b0.z; cnz.y = b1.z;
    cz2.x = a0.w; cz2.y = a1.w;
    rc2.x = LOG2E / b0.w; rc2.y = LOG2E / b1.w;  // inf ok: min() clamp below
  }

  const v2f c128 = splat(128.0f);

  // compile-time |dx| per packed u (u = 1..10): p=0 -> |u-5|, p=1 -> |u-6|
  const int AX0[10] = {4, 3, 2, 1, 0, 1, 2, 3, 4, 5};
  const int AX1[10] = {5, 4, 3, 2, 1, 0, 1, 2, 3, 4};

#pragma unroll 1
  for (int dy = -RAD; dy <= RAD; ++dy) {
    const int ady = dy < 0 ? -dy : dy;
    const float kg_ady = kLG[ady];
    const float* irow = kINVD[ady];
    // per-row scalar hoists
    float il2s[6][PX];
#pragma unroll
    for (int j = 0; j < 6; ++j) {
      const float iv = irow[j];
      il2s[j][0] = fminf(rc2.x * iv, CLAMP2);
      il2s[j][1] = fminf(rc2.y * iv, CLAMP2);
    }
    // packed per-u hoists (adx compile-time)
    v2f il2p[10], sAp[10];
#pragma unroll
    for (int j = 0; j < 10; ++j) {
      il2p[j].x = il2s[AX0[j]][0];
      il2p[j].y = il2s[AX1[j]][1];
      sAp[j].x = kLG[AX0[j]] + kg_ady;
      sAp[j].y = kLG[AX1[j]] + kg_ady;
    }

    const float4* rowA = &s_a[ly + dy][lxbase];
    const float4* rowB = &s_b[ly + dy][lxbase];

    // ---- edge tap u=0 (p=0 only, dx=-5) ----
    {
      const float4 a = rowA[0];
      const float4 b = rowB[0];
      const float d = fmaf(b.x, cnx.x, fmaf(b.y, cny.x, b.z * cnz.x));
      const float lg = __log2f(fmaxf(d, 0.0f));
      const float tt = fabsf(a.w - cz2.x) * il2s[5][0];
      const float e = fmaf(128.0f, lg, (kLG[5] + kg_ady) - tt);
      const float w = __builtin_amdgcn_exp2f(e);
      accx.x = fmaf(a.x, w, accx.x);
      accy.x = fmaf(a.y, w, accy.x);
      accz.x = fmaf(a.z, w, accz.x);
      accw.x += w;
    }
    // ---- packed taps u=1..10 (both pixels valid) ----
#pragma unroll
    for (int j = 0; j < 10; ++j) {
      const float4 a = rowA[j + 1];
      const float4 b = rowB[j + 1];
      const v2f d = splat(b.x) * cnx + (splat(b.y) * cny + splat(b.z) * cnz);
      const v2f dm = __builtin_elementwise_max(d, splat(0.0f));
      v2f lg;
      lg.x = __log2f(dm.x);
      lg.y = __log2f(dm.y);
      const v2f dz = splat(a.w) - cz2;
      const v2f adz = __builtin_elementwise_max(dz, -dz);  // |dz|
      const v2f t1 = sAp[j] - adz * il2p[j];
      const v2f e = c128 * lg + t1;
      v2f w;
      w.x = __builtin_amdgcn_exp2f(e.x);
      w.y = __builtin_amdgcn_exp2f(e.y);
      accx = splat(a.x) * w + accx;
      accy = splat(a.y) * w + accy;
      accz = splat(a.z) * w + accz;
      accw = accw + w;
    }
    // ---- edge tap u=11 (p=1 only, dx=+5) ----
    {
      const float4 a = rowA[11];
      const float4 b = rowB[11];
      const float d = fmaf(b.x, cnx.y, fmaf(b.y, cny.y, b.z * cnz.y));
      const float lg = __log2f(fmaxf(d, 0.0f));
      const float tt = fabsf(a.w - cz2.y) * il2s[5][1];
      const float e = fmaf(128.0f, lg, (kLG[5] + kg_ady) - tt);
      const float w = __builtin_amdgcn_exp2f(e);
      accx.y = fmaf(a.x, w, accx.y);
      accy.y = fmaf(a.y, w, accy.y);
      accz.y = fmaf(a.z, w, accz.y);
      accw.y += w;
    }
  }

  const int oy = by * BY + ty;
  const int pix0 = plane + oy * W + bx * BX + tx * PX;
  {
    const float inv = 1.0f / accw.x;
    float* op = out + pix0 * 3;
    op[0] = accx.x * inv; op[1] = accy.x * inv; op[2] = accz.x * inv;
  }
  {
    const float inv = 1.0f / accw.y;
    float* op = out + (pix0 + 1) * 3;
    op[0] = accx.y * inv; op[1] = accy.y * inv; op[2] = accz.y * inv;
  }
}

extern "C" void kernel_launch(void* const* d_in, const int* in_sizes, int n_in,
                              void* d_out, int out_size, void* d_ws, size_t ws_size,
                              hipStream_t stream) {
  const float* col = (const float*)d_in[0];
  const float* nrm = (const float*)d_in[1];
  const float* zdz = (const float*)d_in[2];
  float* out = (float*)d_out;
  const int H = 1024, W = 1024;
  const int B = in_sizes[0] / (3 * H * W);
  dim3 grid(W / BX, H / BY, B);
  bilateral_kernel<<<grid, dim3(256), 0, stream>>>(col, nrm, zdz, out, H, W);
}

// Round 5
// 353.663 us; speedup vs baseline: 1.0126x; 1.0126x over previous
//
#include <hip/hip_runtime.h>

#define RAD 5
#define BX 32              // output tile width (pixels)
#define BY 32              // output tile height
#define PX 4               // pixels per thread in x
#define NTX 8              // threads in x (NTX*PX == BX)
#define NTY 32             // threads in y (== BY)
#define TW (BX + 2*RAD)    // 42 halo tile width
#define TH (BY + 2*RAD)    // 42 halo tile height
#define TWP (TW + 1)       // 43 padded LDS row stride

#define LOG2E 1.44269504f
#define CLAMP2 14426.950f  // 1e4 * log2(e)

// kLG[|d|] = log2(exp(-d*d/8)) = -d*d/(8*ln2)
__device__ __constant__ const float kLG[6] = {
    0.0f, -0.18033688f, -0.72134752f, -1.62303192f, -2.88539008f, -4.50842200f};
// kINVD[|dy|][|dx|] = 1/sqrt(dy^2+dx^2); center sentinel 1e30 -> min() clamps
__device__ __constant__ const float kINVD[6][6] = {
    {1e30f,       1.0f,        0.5f,        0.33333333f, 0.25f,       0.2f},
    {1.0f,        0.70710678f, 0.44721360f, 0.31622777f, 0.24253563f, 0.19611614f},
    {0.5f,        0.44721360f, 0.35355339f, 0.27735010f, 0.22360680f, 0.18569534f},
    {0.33333333f, 0.31622777f, 0.27735010f, 0.23570226f, 0.2f,        0.17149859f},
    {0.25f,       0.24253563f, 0.22360680f, 0.2f,        0.17677670f, 0.15617376f},
    {0.2f,        0.19611614f, 0.18569534f, 0.17149859f, 0.15617376f, 0.14142136f}};

__global__ __launch_bounds__(256, 2) void bilateral_kernel(
    const float* __restrict__ col, const float* __restrict__ nrm,
    const float* __restrict__ zdz, float* __restrict__ out,
    int H, int W) {
  __shared__ float4 s_a[TH][TWP];  // col.rgb, z
  __shared__ float4 s_b[TH][TWP];  // nrm.xyz, dz

  const int bx = blockIdx.x, by = blockIdx.y, bz = blockIdx.z;
  const int gx0 = bx * BX - RAD;
  const int gy0 = by * BY - RAD;
  const int tid = threadIdx.x;
  const int plane = bz * H * W;

  // ---- stage halo tile into LDS (OOB -> zeros => weight 0, matches mask) ----
  for (int i = tid; i < TH * TW; i += 256) {
    const int r = i / TW;
    const int c = i - r * TW;
    const int gy = gy0 + r, gx = gx0 + c;
    float4 a = make_float4(0.f, 0.f, 0.f, 0.f);
    float4 b = make_float4(0.f, 0.f, 0.f, 0.f);
    if ((unsigned)gy < (unsigned)H && (unsigned)gx < (unsigned)W) {
      const int pix = plane + gy * W + gx;
      const float* cp = col + pix * 3;
      a.x = cp[0]; a.y = cp[1]; a.z = cp[2];
      const float* np_ = nrm + pix * 3;
      b.x = np_[0]; b.y = np_[1]; b.z = np_[2];
      const float* zp = zdz + pix * 2;
      a.w = zp[0]; b.w = zp[1];
    }
    s_a[r][c] = a;
    s_b[r][c] = b;
  }
  __syncthreads();

  const int tx = tid & (NTX - 1);
  const int ty = tid >> 3;
  const int ly = ty + RAD;
  const int lxbase = tx * PX;  // tap x = lxbase + u ; center p at lxbase+RAD+p

  float cnx[PX], cny[PX], cnz[PX], czv[PX], rc2[PX];
  float accx[PX], accy[PX], accz[PX], accw[PX];
#pragma unroll
  for (int p = 0; p < PX; ++p) {
    const float4 a = s_a[ly][lxbase + RAD + p];
    const float4 b = s_b[ly][lxbase + RAD + p];
    cnx[p] = b.x; cny[p] = b.y; cnz[p] = b.z;
    czv[p] = a.w;
    rc2[p] = LOG2E / b.w;  // log2e/cdz (inf ok: min() clamp below)
    accx[p] = 0.f; accy[p] = 0.f; accz[p] = 0.f; accw[p] = 0.f;
  }

#pragma unroll 1
  for (int dy = -RAD; dy <= RAD; ++dy) {
    const int ady = dy < 0 ? -dy : dy;
    const float kg_ady = kLG[ady];      // wave-uniform (SGPR)
    const float* irow = kINVD[ady];     // wave-uniform row pointer
    // per-row hoists: sA wave-uniform (SGPR); il2s per-pixel (VGPR)
    float sA[6];
    float il2s[6][PX];
#pragma unroll
    for (int j = 0; j < 6; ++j) {
      sA[j] = kLG[j] + kg_ady;
      const float iv = irow[j];
#pragma unroll
      for (int p = 0; p < PX; ++p) il2s[j][p] = fminf(rc2[p] * iv, CLAMP2);
    }

    const float4* rowA = &s_a[ly + dy][lxbase];
    const float4* rowB = &s_b[ly + dy][lxbase];

#pragma unroll
    for (int u = 0; u < 2 * RAD + PX; ++u) {  // 14 tap columns serve 4 pixels
      const float4 a = rowA[u];
      const float4 b = rowB[u];
#pragma unroll
      for (int p = 0; p < PX; ++p) {
        const int dx = u - RAD - p;
        if (dx < -RAD || dx > RAD) continue;
        const int adx = dx < 0 ? -dx : dx;
        const float d = fmaf(b.x, cnx[p], fmaf(b.y, cny[p], b.z * cnz[p]));
        const float lg = __log2f(fmaxf(d, 0.0f));  // -inf when d<=0 -> w=0
        const float tt = fabsf(a.w - czv[p]) * il2s[adx][p];
        // w = wn^128 * wxy * wd = exp2(128*lg + (kLG[adx]+kLG[ady]) - tt)
        const float e = fmaf(128.0f, lg, sA[adx] - tt);
        const float w = __builtin_amdgcn_exp2f(e);
        accx[p] = fmaf(a.x, w, accx[p]);
        accy[p] = fmaf(a.y, w, accy[p]);
        accz[p] = fmaf(a.z, w, accz[p]);
        accw[p] += w;
      }
    }
  }

#pragma unroll
  for (int p = 0; p < PX; ++p) {
    const int ox = bx * BX + tx * PX + p;
    const int oy = by * BY + ty;
    const int pix = plane + oy * W + ox;
    const float inv = 1.0f / accw[p];  // center tap weight==1 => accw>=1
    float* op = out + pix * 3;
    op[0] = accx[p] * inv;
    op[1] = accy[p] * inv;
    op[2] = accz[p] * inv;
  }
}

extern "C" void kernel_launch(void* const* d_in, const int* in_sizes, int n_in,
                              void* d_out, int out_size, void* d_ws, size_t ws_size,
                              hipStream_t stream) {
  const float* col = (const float*)d_in[0];
  const float* nrm = (const float*)d_in[1];
  const float* zdz = (const float*)d_in[2];
  float* out = (float*)d_out;
  const int H = 1024, W = 1024;
  const int B = in_sizes[0] / (3 * H * W);
  dim3 grid(W / BX, H / BY, B);
  bilateral_kernel<<<grid, dim3(256), 0, stream>>>(col, nrm, zdz, out, H, W);
}

// Round 6
// 316.485 us; speedup vs baseline: 1.1315x; 1.1175x over previous
//
#include <hip/hip_runtime.h>

#define RAD 5
#define BX 32              // output tile width (pixels)
#define BY 16              // output tile height
#define PX 2               // pixels per thread in x
#define NTX 16             // threads in x (NTX*PX == BX)
#define TW (BX + 2*RAD)    // 42 halo tile width
#define TH (BY + 2*RAD)    // 26 halo tile height
#define TWP (TW + 1)       // 43 padded LDS row stride

#define LOG2E 1.44269504f
#define CLAMP2 14426.950f  // 1e4 * log2(e)
// 128*log2(x) ~= f*(C1 + f*(C2 + f*C3)), f = x-1  (cubic ln series * 128/ln2)
#define PC1 184.664963f
#define PC2 -92.3324814f
#define PC3 61.5549876f

// kLG[|d|] = log2(exp(-d*d/8)) = -d*d/(8*ln2)
__device__ __constant__ const float kLG[6] = {
    0.0f, -0.18033688f, -0.72134752f, -1.62303192f, -2.88539008f, -4.50842200f};
// kINVD[|dy|][|dx|] = 1/sqrt(dy^2+dx^2); center sentinel 1e30 -> min() clamps
__device__ __constant__ const float kINVD[6][6] = {
    {1e30f,       1.0f,        0.5f,        0.33333333f, 0.25f,       0.2f},
    {1.0f,        0.70710678f, 0.44721360f, 0.31622777f, 0.24253563f, 0.19611614f},
    {0.5f,        0.44721360f, 0.35355339f, 0.27735010f, 0.22360680f, 0.18569534f},
    {0.33333333f, 0.31622777f, 0.27735010f, 0.23570226f, 0.2f,        0.17149859f},
    {0.25f,       0.24253563f, 0.22360680f, 0.2f,        0.17677670f, 0.15617376f},
    {0.2f,        0.19611614f, 0.18569534f, 0.17149859f, 0.15617376f, 0.14142136f}};

__global__ __launch_bounds__(256, 4) void bilateral_kernel(
    const float* __restrict__ col, const float* __restrict__ nrm,
    const float* __restrict__ zdz, float* __restrict__ out,
    int H, int W) {
  __shared__ float4 s_w[TH][TWP];  // nrm.xyz, z   (weight inputs, exact fp32)
  __shared__ uint2  s_c[TH][TWP];  // col.rgb as rounded bf16: {g|r packed, b<<16}

  const int bx = blockIdx.x, by = blockIdx.y, bz = blockIdx.z;
  const int gx0 = bx * BX - RAD;
  const int gy0 = by * BY - RAD;
  const int tid = threadIdx.x;
  const int plane = bz * H * W;

  // ---- stage halo tile into LDS (OOB -> zeros => weight 0, matches mask) ----
  for (int i = tid; i < TH * TW; i += 256) {
    const int r = i / TW;
    const int c = i - r * TW;
    const int gy = gy0 + r, gx = gx0 + c;
    float4 wv = make_float4(0.f, 0.f, 0.f, 0.f);
    uint2 cv = make_uint2(0u, 0u);
    if ((unsigned)gy < (unsigned)H && (unsigned)gx < (unsigned)W) {
      const int pix = plane + gy * W + gx;
      const float* np_ = nrm + pix * 3;
      wv.x = np_[0]; wv.y = np_[1]; wv.z = np_[2];
      wv.w = zdz[pix * 2];  // depth
      const float* cp = col + pix * 3;
      // round-to-nearest bf16, kept in fp32 bit positions
      const unsigned ur = (__float_as_uint(cp[0]) + 0x8000u) >> 16;
      const unsigned ug = (__float_as_uint(cp[1]) + 0x8000u) & 0xffff0000u;
      const unsigned ub = (__float_as_uint(cp[2]) + 0x8000u) & 0xffff0000u;
      cv.x = ur | ug;   // r in low half (shl16 to decode), g in high half
      cv.y = ub;        // b already in fp32-high position
    }
    s_w[r][c] = wv;
    s_c[r][c] = cv;
  }
  __syncthreads();

  const int tx = tid & (NTX - 1);
  const int ty = tid >> 4;
  const int ly = ty + RAD;
  const int lxbase = tx * PX;  // tap x = lxbase + u ; center p at lxbase+RAD+p
  const int oy = by * BY + ty;
  const int ox0 = bx * BX + tx * PX;

  float cnx[PX], cny[PX], cnz[PX], czv[PX], rc2[PX];
  float accx[PX], accy[PX], accz[PX], accw[PX];
#pragma unroll
  for (int p = 0; p < PX; ++p) {
    const float4 wv = s_w[ly][lxbase + RAD + p];
    cnx[p] = wv.x; cny[p] = wv.y; cnz[p] = wv.z;
    czv[p] = wv.w;
    const float cdz = zdz[(plane + oy * W + ox0 + p) * 2 + 1];  // center |dz|
    rc2[p] = LOG2E / cdz;  // inf ok: min() clamp below
    accx[p] = 0.f; accy[p] = 0.f; accz[p] = 0.f; accw[p] = 0.f;
  }

#pragma unroll 1
  for (int dy = -RAD; dy <= RAD; ++dy) {
    const int ady = dy < 0 ? -dy : dy;
    const float kg_ady = kLG[ady];      // wave-uniform (SGPR)
    const float* irow = kINVD[ady];     // wave-uniform row pointer
    float sA[6];                         // kLG[adx]+kLG[ady]  (SGPR)
    float il2s[6][PX];
#pragma unroll
    for (int j = 0; j < 6; ++j) {
      sA[j] = kLG[j] + kg_ady;
      const float iv = irow[j];
#pragma unroll
      for (int p = 0; p < PX; ++p) il2s[j][p] = fminf(rc2[p] * iv, CLAMP2);
    }

    const float4* rowW = &s_w[ly + dy][lxbase];
    const uint2* rowC = &s_c[ly + dy][lxbase];

#pragma unroll
    for (int u = 0; u < 2 * RAD + PX; ++u) {  // 12 tap columns serve PX pixels
      const float4 wv = rowW[u];
      const uint2 cv = rowC[u];
      const float tr = __uint_as_float(cv.x << 16);
      const float tg = __uint_as_float(cv.x & 0xffff0000u);
      const float tb = __uint_as_float(cv.y);
#pragma unroll
      for (int p = 0; p < PX; ++p) {
        const int dx = u - RAD - p;
        if (dx < -RAD || dx > RAD) continue;
        const int adx = dx < 0 ? -dx : dx;
        // f = clamp(dot,?) - 1, with the -1 folded into the dot chain
        const float d1 = fmaf(wv.x, cnx[p],
                         fmaf(wv.y, cny[p], fmaf(wv.z, cnz[p], -1.0f)));
        const float f = fmaxf(d1, -1.0f);
        // ct = sA - |z_t - z_c| * il2   (exponent sans normal term)
        const float dz = wv.w - czv[p];
        const float ct = fmaf(-fabsf(dz), il2s[adx][p], sA[adx]);
        // e = 128*log2(dot) + ct via cubic in f; f=-1 -> e<=-338 -> w==0
        const float t1 = fmaf(f, PC3, PC2);
        const float t2 = fmaf(f, t1, PC1);
        const float e = fmaf(f, t2, ct);
        const float w = __builtin_amdgcn_exp2f(e);
        accx[p] = fmaf(tr, w, accx[p]);
        accy[p] = fmaf(tg, w, accy[p]);
        accz[p] = fmaf(tb, w, accz[p]);
        accw[p] += w;
      }
    }
  }

#pragma unroll
  for (int p = 0; p < PX; ++p) {
    const int pix = plane + oy * W + ox0 + p;
    const float inv = 1.0f / accw[p];  // center tap weight==1 => accw>=1
    float* op = out + pix * 3;
    op[0] = accx[p] * inv;
    op[1] = accy[p] * inv;
    op[2] = accz[p] * inv;
  }
}

extern "C" void kernel_launch(void* const* d_in, const int* in_sizes, int n_in,
                              void* d_out, int out_size, void* d_ws, size_t ws_size,
                              hipStream_t stream) {
  const float* col = (const float*)d_in[0];
  const float* nrm = (const float*)d_in[1];
  const float* zdz = (const float*)d_in[2];
  float* out = (float*)d_out;
  const int H = 1024, W = 1024;
  const int B = in_sizes[0] / (3 * H * W);
  dim3 grid(W / BX, H / BY, B);
  bilateral_kernel<<<grid, dim3(256), 0, stream>>>(col, nrm, zdz, out, H, W);
}